// Round 7
// baseline (182.762 us; speedup 1.0000x reference)
//
#include <hip/hip_runtime.h>
#include <stdint.h>

// GraphConvolution: out = relu(x@W1^T + b1 + aggr@W2^T + b2), aggr = sum of 16 neighbor rows.
// R7: R5 structure (its 76.5us k_fused was the best; R6's pipelining+staging both regressed,
// reverted) with the gather restructured: one QUARTER-WAVE per node (256B row == 16 lanes x
// 16B), so each lane accumulates 8 disjoint columns -> NO shfl_xor reduce, NO divergent
// lane<16 write, half the unpack ops (u<<16 / u&0xffff0000). Same load instr count.

#define N_NODES 100000
#define DEG 16

typedef __attribute__((ext_vector_type(8))) short short8;
typedef __attribute__((ext_vector_type(4))) float floatx4;

static __device__ __forceinline__ unsigned short f2bf(float f) {
  union { float f; uint32_t u; } v; v.f = f;
  uint32_t u = v.u;
  return (unsigned short)((u + 0x7fffu + ((u >> 16) & 1u)) >> 16);  // RNE
}
static __device__ __forceinline__ float bflo(uint32_t u) {
  union { uint32_t u; float f; } v; v.u = u << 16; return v.f;
}
static __device__ __forceinline__ float bfhi(uint32_t u) {
  union { uint32_t u; float f; } v; v.u = u & 0xffff0000u; return v.f;
}

// ---- kernel 1: x fp32 -> bf16 Xb[100000][128]  +  W/bias prep (merged) ----
__global__ __launch_bounds__(256) void k_convert(const float* __restrict__ x,
                                                 unsigned short* __restrict__ Xb,
                                                 const float* __restrict__ W1, const float* __restrict__ b1,
                                                 const float* __restrict__ W2, const float* __restrict__ b2,
                                                 unsigned short* __restrict__ Bt, float* __restrict__ bias) {
  int b = blockIdx.x;
  if (b < 12500) {                      // 12500*256 threads == N*32 float4 chunks exactly
    int t = b * 256 + threadIdx.x;
    int n = t >> 5, c4 = t & 31;
    float4 v = *(const float4*)(x + (size_t)n * 128 + (size_t)c4 * 4);
    ushort4 o;
    o.x = f2bf(v.x); o.y = f2bf(v.y); o.z = f2bf(v.z); o.w = f2bf(v.w);
    *(ushort4*)(Xb + (size_t)n * 128 + (size_t)c4 * 4) = o;
  } else {                              // Bt row o = [W1[o,:], W2[o,:]] bf16; bias = b1+b2
    int t = (b - 12500) * 256 + threadIdx.x;  // 0..32767
    int o = t >> 8, k = t & 255;
    float v = (k < 128) ? W1[o * 128 + k] : W2[o * 128 + (k - 128)];
    Bt[t] = f2bf(v);
    if (t < 128) bias[t] = b1[t] + b2[t];
  }
}

// ---- kernel 2: fused gather + GEMM, tile = 32 rows, 4 waves ----
// LDS: aggr only, 32 rows x 256B = 8KB, 16B slots, phys = logical ^ (row&7).
// Gather: quarter-wave g handles node w*8 + round*4 + g; lane owns cols [8*(lane&15), +8).
// GEMM: wave w computes output cols [32w, 32w+32); A kt<4 direct global, kt>=4 from aggr.
__global__ __launch_bounds__(256, 8) void k_fused(const int* __restrict__ nbrs,
                                                  const unsigned short* __restrict__ Xb,
                                                  const unsigned short* __restrict__ Bt,
                                                  const float* __restrict__ bias,
                                                  float* __restrict__ out) {
  __shared__ uint4 aggr4[512];  // 8KB
  char* aggr = (char*)aggr4;
  const int tid = threadIdx.x;
  const int lane = tid & 63;
  const int w = tid >> 6;
  const int g = lane >> 4, c16 = lane & 15;
  const int tile = blockIdx.x * 32;   // 3125*32 = 100000 exactly
  const char* Xbb = (const char*)Xb;  // 256B rows
  const char* Btb = (const char*)Bt;  // 512B rows

  float bcol[2];
#pragma unroll
  for (int ni = 0; ni < 2; ++ni) bcol[ni] = bias[w * 32 + ni * 16 + c16];

  const int nbase = (tile + w * 8) * DEG;
#pragma unroll
  for (int round = 0; round < 2; ++round) {
    // lane l holds: neighbor (l&15) of node w*8+round*4+(l>>4)  (coalesced dword load)
    int midx = nbrs[nbase + round * 64 + lane];
    float a8[8] = {0.f, 0.f, 0.f, 0.f, 0.f, 0.f, 0.f, 0.f};
#pragma unroll
    for (int j = 0; j < DEG; ++j) {
      int nb = __shfl(midx, g * 16 + j);  // neighbor j of this quarter's node
      uint4 pv = *(const uint4*)(Xbb + (size_t)nb * 256 + c16 * 16);  // full-row, quarter-coalesced
      a8[0] += bflo(pv.x); a8[1] += bfhi(pv.x);
      a8[2] += bflo(pv.y); a8[3] += bfhi(pv.y);
      a8[4] += bflo(pv.z); a8[5] += bfhi(pv.z);
      a8[6] += bflo(pv.w); a8[7] += bfhi(pv.w);
    }
    // pack 8 f32 -> 4 dwords, full-wave 16B/lane LDS write (no divergence, no reduce)
    int row = w * 8 + round * 4 + g;
    uint4 wv;
    wv.x = (uint32_t)f2bf(a8[0]) | ((uint32_t)f2bf(a8[1]) << 16);
    wv.y = (uint32_t)f2bf(a8[2]) | ((uint32_t)f2bf(a8[3]) << 16);
    wv.z = (uint32_t)f2bf(a8[4]) | ((uint32_t)f2bf(a8[5]) << 16);
    wv.w = (uint32_t)f2bf(a8[6]) | ((uint32_t)f2bf(a8[7]) << 16);
    *(uint4*)(aggr + row * 256 + ((c16 ^ (row & 7)) * 16)) = wv;
  }

  __syncthreads();  // aggr visible to all waves

  // ---- GEMM: K=256 (kt 0-3 = x direct from global; kt 4-7 = aggr from LDS), B direct ----
  floatx4 acc[2][2];
#pragma unroll
  for (int mi = 0; mi < 2; ++mi)
#pragma unroll
    for (int ni = 0; ni < 2; ++ni) acc[mi][ni] = (floatx4){0.f, 0.f, 0.f, 0.f};

#pragma unroll
  for (int kt = 0; kt < 8; ++kt) {
    short8 a[2], b[2];
#pragma unroll
    for (int mi = 0; mi < 2; ++mi) {
      int row = mi * 16 + c16;  // A-frag: row = lane&15 (+16), k-half = g
      if (kt < 4) {
        a[mi] = *(const short8*)(Xbb + (size_t)(tile + row) * 256 + kt * 64 + g * 16);
      } else {
        int slot = (((kt - 4) * 4 + g) ^ (row & 7)) * 16;
        a[mi] = *(const short8*)(aggr + row * 256 + slot);
      }
    }
#pragma unroll
    for (int ni = 0; ni < 2; ++ni) {
      int o = w * 32 + ni * 16 + c16;  // B-frag: col = lane&15, k-half = g (L1/L2-hot)
      b[ni] = *(const short8*)(Btb + (size_t)o * 512 + kt * 64 + g * 16);
    }
    __builtin_amdgcn_s_setprio(1);
    acc[0][0] = __builtin_amdgcn_mfma_f32_16x16x32_bf16(a[0], b[0], acc[0][0], 0, 0, 0);
    acc[0][1] = __builtin_amdgcn_mfma_f32_16x16x32_bf16(a[0], b[1], acc[0][1], 0, 0, 0);
    acc[1][0] = __builtin_amdgcn_mfma_f32_16x16x32_bf16(a[1], b[0], acc[1][0], 0, 0, 0);
    acc[1][1] = __builtin_amdgcn_mfma_f32_16x16x32_bf16(a[1], b[1], acc[1][1], 0, 0, 0);
    __builtin_amdgcn_s_setprio(0);
  }

  // ---- epilogue: C/D layout col=lane&15, row=g*4+reg (m89-verified); bias+relu ----
#pragma unroll
  for (int mi = 0; mi < 2; ++mi) {
    int rbase = tile + mi * 16 + g * 4;
#pragma unroll
    for (int r = 0; r < 4; ++r) {
      float* orow = out + (size_t)(rbase + r) * 128 + w * 32 + c16;
#pragma unroll
      for (int ni = 0; ni < 2; ++ni) {
        float vv = acc[mi][ni][r] + bcol[ni];
        orow[ni * 16] = vv > 0.f ? vv : 0.f;
      }
    }
  }
}

extern "C" void kernel_launch(void* const* d_in, const int* in_sizes, int n_in,
                              void* d_out, int out_size, void* d_ws, size_t ws_size,
                              hipStream_t stream) {
  const int* nbrs  = (const int*)d_in[0];
  const float* x   = (const float*)d_in[1];
  const float* W1  = (const float*)d_in[2];
  const float* b1  = (const float*)d_in[3];
  const float* W2  = (const float*)d_in[4];
  const float* b2  = (const float*)d_in[5];
  float* out = (float*)d_out;

  // ws layout: Xb bf16 [100000][128] | Bt bf16 [128][256] | bias f32 [128]
  unsigned short* Xb = (unsigned short*)d_ws;
  unsigned short* Bt = Xb + (size_t)N_NODES * 128;
  float* bias = (float*)(Bt + 128 * 256);

  k_convert<<<12628, 256, 0, stream>>>(x, Xb, W1, b1, W2, b2, Bt, bias);
  k_fused<<<3125, 256, 0, stream>>>(nbrs, Xb, Bt, bias, out);
}